// Round 4
// baseline (384.782 us; speedup 1.0000x reference)
//
#include <hip/hip_runtime.h>

#define DIM 128
#define CAP 128
#define OVF_CAP (1 << 18)
#define HIST_BINS 5000
#define HIST_G 10          // HIST_G * HIST_BINS >= N
#define HIST_R 16          // edge-chunk replicas per bin range

// ---- bf16 helpers (packed 2x bf16 in a uint; lo = dim 2*lane, hi = 2*lane+1) ----
__device__ __forceinline__ float bflo(unsigned u) { return __uint_as_float(u << 16); }
__device__ __forceinline__ float bfhi(unsigned u) { return __uint_as_float(u & 0xffff0000u); }
__device__ __forceinline__ unsigned packbf(float a, float b) {
    unsigned ua = __float_as_uint(a), ub = __float_as_uint(b);
    ua += 0x7fffu + ((ua >> 16) & 1u);   // RNE
    ub += 0x7fffu + ((ub >> 16) & 1u);
    return (ua >> 16) | (ub & 0xffff0000u);
}

// One launch, four independent roles:
//  [0, nb_hist)             : LDS-privatized src-degree histogram
//  [.., +nb_fill)           : bucketed dst-CSR fill (cur atomic + u16 scatter)
//  [.., +nb_norm)           : row L2-normalize features -> packed bf16 Xb
//  [.., +nb_copy)           : preference passthrough copy (float4)
__global__ void mega_kernel(const float* __restrict__ features,
                            const float* __restrict__ preference,
                            const int* __restrict__ src, const int* __restrict__ dst,
                            unsigned* __restrict__ Xb, int* __restrict__ deg,
                            int* __restrict__ cur, unsigned short* __restrict__ csr,
                            int* __restrict__ ovf_n, int2* __restrict__ ovf,
                            float* __restrict__ out_pref,
                            int N, int E, int NU,
                            int nb_hist, int nb_fill, int nb_norm) {
    __shared__ int hbin[HIST_BINS];
    int b = blockIdx.x;
    int tid = threadIdx.x;

    if (b < nb_hist) {
        int g = b / HIST_R, r = b % HIST_R;
        int lo = g * HIST_BINS;
        for (int i = tid; i < HIST_BINS; i += 256) hbin[i] = 0;
        __syncthreads();
        int chunk = (E + HIST_R - 1) / HIST_R;
        int e0 = r * chunk, e1 = min(E, e0 + chunk);
        for (int e = e0 + tid; e < e1; e += 256) {
            int s = src[e], d = dst[e];
            if (s != d) {
                unsigned rel = (unsigned)(s - lo);
                if (rel < HIST_BINS) atomicAdd(&hbin[rel], 1);
            }
        }
        __syncthreads();
        for (int i = tid; i < HIST_BINS; i += 256) {
            int v = hbin[i];
            if (v && (lo + i) < N) atomicAdd(&deg[lo + i], v);
        }
        return;
    }
    b -= nb_hist;
    if (b < nb_fill) {
        int e = b * 256 + tid;
        if (e < E) {
            int s = src[e], d = dst[e];
            if (s != d) {
                int pos = atomicAdd(&cur[d], 1);
                if (pos < CAP) {
                    csr[(size_t)d * CAP + pos] = (unsigned short)s;
                } else {
                    int o = atomicAdd(ovf_n, 1);
                    if (o < OVF_CAP) ovf[o] = make_int2(s, d);
                }
            }
        }
        return;
    }
    b -= nb_fill;
    if (b < nb_norm) {
        int t = b * 256 + tid;
        int row = t >> 6;
        if (row < N) {
            int lane = t & 63;
            float2 v = ((const float2*)(features + (size_t)row * DIM))[lane];
            float ss = v.x * v.x + v.y * v.y;
            #pragma unroll
            for (int off = 32; off >= 1; off >>= 1) ss += __shfl_xor(ss, off, 64);
            float scale = 1.0f / fmaxf(sqrtf(ss), 1e-12f);
            Xb[(size_t)row * 64 + lane] = packbf(v.x * scale, v.y * scale);
        }
        return;
    }
    b -= nb_norm;
    {
        int i = b * 256 + tid;
        int n4 = NU * DIM / 4;
        if (i < n4) ((float4*)out_pref)[i] = ((const float4*)preference)[i];
    }
}

__global__ void dis_kernel(const int* __restrict__ deg, float* __restrict__ dis, int n) {
    int i = blockIdx.x * blockDim.x + threadIdx.x;
    if (i >= n) return;
    int d = deg[i];
    dis[i] = (d > 0) ? rsqrtf((float)d) : 0.0f;
}

// Wave-batched gather: lane l preloads (src, weight) for edge slot l, then the
// whole wave shfl-broadcasts them; only the 256B row gather touches memory per edge.
__device__ __forceinline__ float2 gather_node(const unsigned* __restrict__ X,
                                              const unsigned short* __restrict__ csr,
                                              const int* __restrict__ cur,
                                              const float* __restrict__ dis,
                                              const int* __restrict__ ovf_n,
                                              const int2* __restrict__ ovf,
                                              int node, int lane) {
    int cnt = min(cur[node], CAP);
    float dd = dis[node];
    size_t base = (size_t)node * CAP;
    float ax0 = 0, ay0 = 0, ax1 = 0, ay1 = 0, ax2 = 0, ay2 = 0, ax3 = 0, ay3 = 0;
    for (int b0 = 0; b0 < cnt; b0 += 64) {
        int m = min(cnt - b0, 64);
        int sl = 0; float wl = 0.0f;
        if (lane < m) { sl = csr[base + b0 + lane]; wl = dis[sl] * dd; }
        int i = 0;
        for (; i + 3 < m; i += 4) {
            int s0 = __shfl(sl, i, 64),     s1 = __shfl(sl, i + 1, 64);
            int s2 = __shfl(sl, i + 2, 64), s3 = __shfl(sl, i + 3, 64);
            float w0 = __shfl(wl, i, 64),     w1 = __shfl(wl, i + 1, 64);
            float w2 = __shfl(wl, i + 2, 64), w3 = __shfl(wl, i + 3, 64);
            unsigned u0 = X[(size_t)s0 * 64 + lane];
            unsigned u1 = X[(size_t)s1 * 64 + lane];
            unsigned u2 = X[(size_t)s2 * 64 + lane];
            unsigned u3 = X[(size_t)s3 * 64 + lane];
            ax0 += w0 * bflo(u0); ay0 += w0 * bfhi(u0);
            ax1 += w1 * bflo(u1); ay1 += w1 * bfhi(u1);
            ax2 += w2 * bflo(u2); ay2 += w2 * bfhi(u2);
            ax3 += w3 * bflo(u3); ay3 += w3 * bfhi(u3);
        }
        for (; i < m; ++i) {
            int s0 = __shfl(sl, i, 64); float w0 = __shfl(wl, i, 64);
            unsigned u0 = X[(size_t)s0 * 64 + lane];
            ax0 += w0 * bflo(u0); ay0 += w0 * bfhi(u0);
        }
    }
    float2 acc = {ax0 + ax1 + ax2 + ax3, ay0 + ay1 + ay2 + ay3};
    int on = min(*ovf_n, OVF_CAP);   // practically 0; formal correctness
    for (int k = 0; k < on; ++k) {
        int2 eo = ovf[k];
        if (eo.y == node) {
            float w = dis[eo.x] * dd;
            unsigned u = X[(size_t)eo.x * 64 + lane];
            acc.x += w * bflo(u); acc.y += w * bfhi(u);
        }
    }
    return acc;
}

__global__ void conv1_kernel(const unsigned* __restrict__ Xb, const unsigned short* __restrict__ csr,
                             const int* __restrict__ cur, const float* __restrict__ dis,
                             const int* __restrict__ ovf_n, const int2* __restrict__ ovf,
                             unsigned* __restrict__ Hb, int n) {
    int node = (blockIdx.x * blockDim.x + threadIdx.x) >> 6;
    if (node >= n) return;
    int lane = threadIdx.x & 63;
    float2 acc = gather_node(Xb, csr, cur, dis, ovf_n, ovf, node, lane);
    Hb[(size_t)node * 64 + lane] = packbf(acc.x, acc.y);
}

__global__ void conv2_kernel(const unsigned* __restrict__ Hb, const unsigned* __restrict__ Xb,
                             const unsigned short* __restrict__ csr,
                             const int* __restrict__ cur, const float* __restrict__ dis,
                             const int* __restrict__ ovf_n, const int2* __restrict__ ovf,
                             float* __restrict__ out, int n) {
    int node = (blockIdx.x * blockDim.x + threadIdx.x) >> 6;
    if (node >= n) return;
    int lane = threadIdx.x & 63;
    float2 acc = gather_node(Hb, csr, cur, dis, ovf_n, ovf, node, lane);
    unsigned hb = Hb[(size_t)node * 64 + lane];
    unsigned xb = Xb[(size_t)node * 64 + lane];
    float2 o;
    o.x = acc.x + bflo(hb) + bflo(xb);
    o.y = acc.y + bfhi(hb) + bfhi(xb);
    ((float2*)(out + (size_t)node * DIM))[lane] = o;
}

extern "C" void kernel_launch(void* const* d_in, const int* in_sizes, int n_in,
                              void* d_out, int out_size, void* d_ws, size_t ws_size,
                              hipStream_t stream) {
    const float* features   = (const float*)d_in[0];
    const float* preference = (const float*)d_in[1];
    const int*   edge_index = (const int*)d_in[2];

    const int N  = in_sizes[0] / DIM;   // 50000
    const int NU = in_sizes[1] / DIM;   // 10000
    const int E  = in_sizes[2] / 2;     // 1600000

    const int* src = edge_index;
    const int* dst = edge_index + E;
    float* out = (float*)d_out;

    // workspace layout (~41 MB)
    char* p = (char*)d_ws;
    unsigned* Xb = (unsigned*)p;              p += (size_t)N * 64 * sizeof(unsigned);
    unsigned* Hb = (unsigned*)p;              p += (size_t)N * 64 * sizeof(unsigned);
    unsigned short* csr = (unsigned short*)p; p += (size_t)N * CAP * sizeof(unsigned short);
    int*   deg  = (int*)p;                    p += (size_t)N * sizeof(int);
    int*   cur  = (int*)p;                    p += (size_t)N * sizeof(int);
    float* dis  = (float*)p;                  p += (size_t)N * sizeof(float);
    int*   ovf_n = (int*)p;                   p += 4 * sizeof(int);
    int2*  ovf  = (int2*)p;                   p += (size_t)OVF_CAP * sizeof(int2);

    hipMemsetAsync(deg, 0, (size_t)N * sizeof(int), stream);
    hipMemsetAsync(cur, 0, (size_t)N * sizeof(int), stream);
    hipMemsetAsync(ovf_n, 0, sizeof(int), stream);

    int nb_hist = HIST_G * HIST_R;
    int nb_fill = (E + 255) / 256;
    int nb_norm = (N * 64 + 255) / 256;
    int nb_copy = (NU * DIM / 4 + 255) / 256;
    int grid = nb_hist + nb_fill + nb_norm + nb_copy;

    mega_kernel<<<grid, 256, 0, stream>>>(features, preference, src, dst,
                                          Xb, deg, cur, csr, ovf_n, ovf,
                                          out + (size_t)N * DIM,
                                          N, E, NU, nb_hist, nb_fill, nb_norm);

    dis_kernel<<<(N + 255) / 256, 256, 0, stream>>>(deg, dis, N);

    int blocks = (N * 64 + 255) / 256;
    conv1_kernel<<<blocks, 256, 0, stream>>>(Xb, csr, cur, dis, ovf_n, ovf, Hb, N);
    conv2_kernel<<<blocks, 256, 0, stream>>>(Hb, Xb, csr, cur, dis, ovf_n, ovf, out, N);
}

// Round 5
// 286.009 us; speedup vs baseline: 1.3454x; 1.3454x over previous
//
#include <hip/hip_runtime.h>

#define DIM 128
#define CAP 128
#define PAD 16            // pad atomics to 64B lines: counter i lives at [i*PAD]
#define OVF_CAP (1 << 18)

// ---- bf16 helpers (packed 2x bf16 in a uint; lo = dim 2*lane, hi = 2*lane+1) ----
__device__ __forceinline__ float bflo(unsigned u) { return __uint_as_float(u << 16); }
__device__ __forceinline__ float bfhi(unsigned u) { return __uint_as_float(u & 0xffff0000u); }
__device__ __forceinline__ unsigned packbf(float a, float b) {
    unsigned ua = __float_as_uint(a), ub = __float_as_uint(b);
    ua += 0x7fffu + ((ua >> 16) & 1u);   // RNE
    ub += 0x7fffu + ((ub >> 16) & 1u);
    return (ua >> 16) | (ub & 0xffff0000u);
}

// One launch, three independent roles (no LDS, so no occupancy penalty):
//  [0, nb_fill) : per-edge src-degree atomic + bucketed dst-CSR fill (padded counters)
//  [.., +nb_norm): row L2-normalize features -> packed bf16 Xb
//  [.., +nb_copy): preference passthrough copy (float4)
__global__ void prep_kernel(const float* __restrict__ features,
                            const float* __restrict__ preference,
                            const int* __restrict__ src, const int* __restrict__ dst,
                            unsigned* __restrict__ Xb, int* __restrict__ deg,
                            int* __restrict__ cur, unsigned short* __restrict__ csr,
                            int* __restrict__ ovf_n, int2* __restrict__ ovf,
                            float* __restrict__ out_pref,
                            int N, int E, int NU, int nb_fill, int nb_norm) {
    int b = blockIdx.x;
    int tid = threadIdx.x;

    if (b < nb_fill) {
        int e = b * 256 + tid;
        if (e < E) {
            int s = src[e], d = dst[e];
            if (s != d) {
                atomicAdd(&deg[(size_t)s * PAD], 1);
                int pos = atomicAdd(&cur[(size_t)d * PAD], 1);
                if (pos < CAP) {
                    csr[(size_t)d * CAP + pos] = (unsigned short)s;
                } else {
                    int o = atomicAdd(ovf_n, 1);
                    if (o < OVF_CAP) ovf[o] = make_int2(s, d);
                }
            }
        }
        return;
    }
    b -= nb_fill;
    if (b < nb_norm) {
        int t = b * 256 + tid;
        int row = t >> 6;
        if (row < N) {
            int lane = t & 63;
            float2 v = ((const float2*)(features + (size_t)row * DIM))[lane];
            float ss = v.x * v.x + v.y * v.y;
            #pragma unroll
            for (int off = 32; off >= 1; off >>= 1) ss += __shfl_xor(ss, off, 64);
            float scale = 1.0f / fmaxf(sqrtf(ss), 1e-12f);
            Xb[(size_t)row * 64 + lane] = packbf(v.x * scale, v.y * scale);
        }
        return;
    }
    b -= nb_norm;
    {
        int i = b * 256 + tid;
        int n4 = NU * DIM / 4;
        if (i < n4) ((float4*)out_pref)[i] = ((const float4*)preference)[i];
    }
}

__global__ void dis_kernel(const int* __restrict__ deg, float* __restrict__ dis, int n) {
    int i = blockIdx.x * blockDim.x + threadIdx.x;
    if (i >= n) return;
    int d = deg[(size_t)i * PAD];
    dis[i] = (d > 0) ? rsqrtf((float)d) : 0.0f;
}

// Wave-batched gather: lane l preloads (src, weight) for edge slot l, then the
// whole wave shfl-broadcasts them; only the 256B row gather touches memory per edge.
__device__ __forceinline__ float2 gather_node(const unsigned* __restrict__ X,
                                              const unsigned short* __restrict__ csr,
                                              const int* __restrict__ cur,
                                              const float* __restrict__ dis,
                                              const int* __restrict__ ovf_n,
                                              const int2* __restrict__ ovf,
                                              int node, int lane) {
    int cnt = min(cur[(size_t)node * PAD], CAP);
    float dd = dis[node];
    size_t base = (size_t)node * CAP;
    float ax0 = 0, ay0 = 0, ax1 = 0, ay1 = 0, ax2 = 0, ay2 = 0, ax3 = 0, ay3 = 0;
    for (int b0 = 0; b0 < cnt; b0 += 64) {
        int m = min(cnt - b0, 64);
        int sl = 0; float wl = 0.0f;
        if (lane < m) { sl = csr[base + b0 + lane]; wl = dis[sl] * dd; }
        int i = 0;
        for (; i + 3 < m; i += 4) {
            int s0 = __shfl(sl, i, 64),     s1 = __shfl(sl, i + 1, 64);
            int s2 = __shfl(sl, i + 2, 64), s3 = __shfl(sl, i + 3, 64);
            float w0 = __shfl(wl, i, 64),     w1 = __shfl(wl, i + 1, 64);
            float w2 = __shfl(wl, i + 2, 64), w3 = __shfl(wl, i + 3, 64);
            unsigned u0 = X[(size_t)s0 * 64 + lane];
            unsigned u1 = X[(size_t)s1 * 64 + lane];
            unsigned u2 = X[(size_t)s2 * 64 + lane];
            unsigned u3 = X[(size_t)s3 * 64 + lane];
            ax0 += w0 * bflo(u0); ay0 += w0 * bfhi(u0);
            ax1 += w1 * bflo(u1); ay1 += w1 * bfhi(u1);
            ax2 += w2 * bflo(u2); ay2 += w2 * bfhi(u2);
            ax3 += w3 * bflo(u3); ay3 += w3 * bfhi(u3);
        }
        for (; i < m; ++i) {
            int s0 = __shfl(sl, i, 64); float w0 = __shfl(wl, i, 64);
            unsigned u0 = X[(size_t)s0 * 64 + lane];
            ax0 += w0 * bflo(u0); ay0 += w0 * bfhi(u0);
        }
    }
    float2 acc = {ax0 + ax1 + ax2 + ax3, ay0 + ay1 + ay2 + ay3};
    int on = min(*ovf_n, OVF_CAP);   // practically 0; formal correctness
    for (int k = 0; k < on; ++k) {
        int2 eo = ovf[k];
        if (eo.y == node) {
            float w = dis[eo.x] * dd;
            unsigned u = X[(size_t)eo.x * 64 + lane];
            acc.x += w * bflo(u); acc.y += w * bfhi(u);
        }
    }
    return acc;
}

__global__ void conv1_kernel(const unsigned* __restrict__ Xb, const unsigned short* __restrict__ csr,
                             const int* __restrict__ cur, const float* __restrict__ dis,
                             const int* __restrict__ ovf_n, const int2* __restrict__ ovf,
                             unsigned* __restrict__ Hb, int n) {
    int node = (blockIdx.x * blockDim.x + threadIdx.x) >> 6;
    if (node >= n) return;
    int lane = threadIdx.x & 63;
    float2 acc = gather_node(Xb, csr, cur, dis, ovf_n, ovf, node, lane);
    Hb[(size_t)node * 64 + lane] = packbf(acc.x, acc.y);
}

__global__ void conv2_kernel(const unsigned* __restrict__ Hb, const unsigned* __restrict__ Xb,
                             const unsigned short* __restrict__ csr,
                             const int* __restrict__ cur, const float* __restrict__ dis,
                             const int* __restrict__ ovf_n, const int2* __restrict__ ovf,
                             float* __restrict__ out, int n) {
    int node = (blockIdx.x * blockDim.x + threadIdx.x) >> 6;
    if (node >= n) return;
    int lane = threadIdx.x & 63;
    float2 acc = gather_node(Hb, csr, cur, dis, ovf_n, ovf, node, lane);
    unsigned hb = Hb[(size_t)node * 64 + lane];
    unsigned xb = Xb[(size_t)node * 64 + lane];
    float2 o;
    o.x = acc.x + bflo(hb) + bflo(xb);
    o.y = acc.y + bfhi(hb) + bfhi(xb);
    ((float2*)(out + (size_t)node * DIM))[lane] = o;
}

extern "C" void kernel_launch(void* const* d_in, const int* in_sizes, int n_in,
                              void* d_out, int out_size, void* d_ws, size_t ws_size,
                              hipStream_t stream) {
    const float* features   = (const float*)d_in[0];
    const float* preference = (const float*)d_in[1];
    const int*   edge_index = (const int*)d_in[2];

    const int N  = in_sizes[0] / DIM;   // 50000
    const int NU = in_sizes[1] / DIM;   // 10000
    const int E  = in_sizes[2] / 2;     // 1600000

    const int* src = edge_index;
    const int* dst = edge_index + E;
    float* out = (float*)d_out;

    // workspace layout (~46 MB; ws >= 55 MB proven in round 2)
    char* p = (char*)d_ws;
    unsigned* Xb = (unsigned*)p;              p += (size_t)N * 64 * sizeof(unsigned);
    unsigned* Hb = (unsigned*)p;              p += (size_t)N * 64 * sizeof(unsigned);
    unsigned short* csr = (unsigned short*)p; p += (size_t)N * CAP * sizeof(unsigned short);
    int*   deg  = (int*)p;                    p += (size_t)N * PAD * sizeof(int);
    int*   cur  = (int*)p;                    p += (size_t)N * PAD * sizeof(int);
    float* dis  = (float*)p;                  p += (size_t)N * sizeof(float);
    int*   ovf_n = (int*)p;                   p += 4 * sizeof(int);
    int2*  ovf  = (int2*)p;                   p += (size_t)OVF_CAP * sizeof(int2);

    hipMemsetAsync(deg, 0, (size_t)N * PAD * sizeof(int), stream);
    hipMemsetAsync(cur, 0, (size_t)N * PAD * sizeof(int), stream);
    hipMemsetAsync(ovf_n, 0, sizeof(int), stream);

    int nb_fill = (E + 255) / 256;
    int nb_norm = (N * 64 + 255) / 256;
    int nb_copy = (NU * DIM / 4 + 255) / 256;
    int grid = nb_fill + nb_norm + nb_copy;

    prep_kernel<<<grid, 256, 0, stream>>>(features, preference, src, dst,
                                          Xb, deg, cur, csr, ovf_n, ovf,
                                          out + (size_t)N * DIM,
                                          N, E, NU, nb_fill, nb_norm);

    dis_kernel<<<(N + 255) / 256, 256, 0, stream>>>(deg, dis, N);

    int blocks = (N * 64 + 255) / 256;
    conv1_kernel<<<blocks, 256, 0, stream>>>(Xb, csr, cur, dis, ovf_n, ovf, Hb, N);
    conv2_kernel<<<blocks, 256, 0, stream>>>(Hb, Xb, csr, cur, dis, ovf_n, ovf, out, N);
}

// Round 6
// 231.618 us; speedup vs baseline: 1.6613x; 1.2348x over previous
//
#include <hip/hip_runtime.h>

#define DIM 128
#define CAP 96              // csr slots per node (mean in-deg 32, +11 sigma, ovf fallback)
#define BCAP 10240          // region entries per 256-node bucket (mean ~8182, +23 sigma)
#define EPB 8192            // edges per scatter block
#define OVFD_CAP 32768
#define OVFS_CAP 32768

// ---- bf16 helpers (packed 2x bf16 in a uint; lo = dim 2*lane, hi = 2*lane+1) ----
__device__ __forceinline__ float bflo(unsigned u) { return __uint_as_float(u << 16); }
__device__ __forceinline__ float bfhi(unsigned u) { return __uint_as_float(u & 0xffff0000u); }
__device__ __forceinline__ unsigned packbf(float a, float b) {
    unsigned ua = __float_as_uint(a), ub = __float_as_uint(b);
    ua += 0x7fffu + ((ua >> 16) & 1u);   // RNE
    ub += 0x7fffu + ((ub >> 16) & 1u);
    return (ua >> 16) | (ub & 0xffff0000u);
}

// Roles: [0,nb_scat): block counting-sort of EPB edges into 256-node buckets
//        [..,+nb_norm): row L2-normalize features -> packed bf16 Xb
//        [..,+nb_copy): preference passthrough (float4)
__global__ void prep_kernel(const float* __restrict__ features,
                            const float* __restrict__ preference,
                            const int* __restrict__ src, const int* __restrict__ dst,
                            unsigned* __restrict__ Xb,
                            unsigned* __restrict__ regionD, unsigned char* __restrict__ regionS,
                            int* __restrict__ gcursD, int* __restrict__ gcursS,
                            int* __restrict__ ovfD_n, int2* __restrict__ ovfD,
                            int* __restrict__ ovfS_n, int* __restrict__ ovfS,
                            float* __restrict__ out_pref,
                            int N, int E, int NU, int nb, int nb_scat, int nb_norm) {
    __shared__ unsigned histD[256], histS[256];
    __shared__ unsigned scanD[256], scanS[256];
    __shared__ unsigned cursD[256], cursS[256];
    __shared__ unsigned baseD[256], baseS[256];
    __shared__ unsigned stageD[EPB];          // 32 KB: (dLow8<<16)|src16, dst-bucket-grouped
    __shared__ unsigned char stageS[EPB];     // 8 KB: sLow8, src-bucket-grouped
    int b = blockIdx.x, tid = threadIdx.x;

    if (b < nb_scat) {
        int e0 = b * EPB;
        int m = min(E - e0, EPB);
        histD[tid] = 0; histS[tid] = 0;
        __syncthreads();
        for (int j = tid; j < m; j += 256) {
            int s = src[e0 + j], d = dst[e0 + j];
            if (s != d) { atomicAdd(&histD[d >> 8], 1u); atomicAdd(&histS[s >> 8], 1u); }
        }
        __syncthreads();
        if (tid == 0) {                       // serial exclusive scan over nb bins
            unsigned aD = 0, aS = 0;
            for (int i = 0; i < nb; ++i) {
                scanD[i] = aD; aD += histD[i];
                scanS[i] = aS; aS += histS[i];
            }
        }
        __syncthreads();
        if (tid < nb) { cursD[tid] = scanD[tid]; cursS[tid] = scanS[tid]; }
        __syncthreads();
        for (int j = tid; j < m; j += 256) {  // stage into LDS, grouped by bucket
            int s = src[e0 + j], d = dst[e0 + j];
            if (s != d) {
                unsigned p = atomicAdd(&cursD[d >> 8], 1u);
                stageD[p] = ((unsigned)(d & 255) << 16) | (unsigned)s;
                unsigned q = atomicAdd(&cursS[s >> 8], 1u);
                stageS[q] = (unsigned char)(s & 255);
            }
        }
        __syncthreads();
        if (tid < nb) {                       // claim global region runs (2 atomics/bucket)
            unsigned c = histD[tid];
            baseD[tid] = c ? (unsigned)atomicAdd(&gcursD[tid], (int)c) : 0u;
            unsigned c2 = histS[tid];
            baseS[tid] = c2 ? (unsigned)atomicAdd(&gcursS[tid], (int)c2) : 0u;
        }
        __syncthreads();
        for (int bk = 0; bk < nb; ++bk) {     // coalesced flush per bucket
            unsigned st = scanD[bk], c = histD[bk], gb = baseD[bk];
            for (unsigned j = tid; j < c; j += 256) {
                unsigned ent = stageD[st + j];
                unsigned gp = gb + j;
                if (gp < BCAP) regionD[(size_t)bk * BCAP + gp] = ent;
                else {
                    int o = atomicAdd(ovfD_n, 1);
                    if (o < OVFD_CAP) ovfD[o] = make_int2((int)(ent & 0xFFFFu), (bk << 8) | (int)(ent >> 16));
                }
            }
            unsigned st2 = scanS[bk], c2 = histS[bk], gb2 = baseS[bk];
            for (unsigned j = tid; j < c2; j += 256) {
                unsigned char sl = stageS[st2 + j];
                unsigned gp = gb2 + j;
                if (gp < BCAP) regionS[(size_t)bk * BCAP + gp] = sl;
                else {
                    int o = atomicAdd(ovfS_n, 1);
                    if (o < OVFS_CAP) ovfS[o] = (bk << 8) | (int)sl;
                }
            }
        }
        return;
    }
    b -= nb_scat;
    if (b < nb_norm) {
        int t = b * 256 + tid;
        int row = t >> 6;
        if (row < N) {
            int lane = t & 63;
            float2 v = ((const float2*)(features + (size_t)row * DIM))[lane];
            float ss = v.x * v.x + v.y * v.y;
            #pragma unroll
            for (int off = 32; off >= 1; off >>= 1) ss += __shfl_xor(ss, off, 64);
            float scale = 1.0f / fmaxf(sqrtf(ss), 1e-12f);
            Xb[(size_t)row * 64 + lane] = packbf(v.x * scale, v.y * scale);
        }
        return;
    }
    b -= nb_norm;
    {
        int i = b * 256 + tid;
        int n4 = NU * DIM / 4;
        if (i < n4) ((float4*)out_pref)[i] = ((const float4*)preference)[i];
    }
}

// Roles: [0,nb): per-dst-bucket slot assignment -> csr + cnt (writes land in a
//               48KB local-L2 window); [nb,2nb): per-src-bucket degree count -> dis.
__global__ void finalize_kernel(const unsigned* __restrict__ regionD,
                                const unsigned char* __restrict__ regionS,
                                const int* __restrict__ gcursD, const int* __restrict__ gcursS,
                                unsigned short* __restrict__ csr, int* __restrict__ cnt,
                                float* __restrict__ dis,
                                int* __restrict__ ovfD_n, int2* __restrict__ ovfD,
                                const int* __restrict__ ovfS_n, const int* __restrict__ ovfS,
                                int N, int nb) {
    __shared__ unsigned c256[256];
    int b = blockIdx.x, tid = threadIdx.x;
    if (b < nb) {           // dst role
        c256[tid] = 0;
        __syncthreads();
        int m = min(gcursD[b], BCAP);
        for (int j = tid; j < m; j += 256) {
            unsigned ent = regionD[(size_t)b * BCAP + j];
            unsigned dLow = ent >> 16;
            int s = (int)(ent & 0xFFFFu);
            unsigned pos = atomicAdd(&c256[dLow], 1u);
            int node = (b << 8) | (int)dLow;
            if (pos < CAP) csr[(size_t)node * CAP + pos] = (unsigned short)s;
            else {
                int o = atomicAdd(ovfD_n, 1);
                if (o < OVFD_CAP) ovfD[o] = make_int2(s, node);
            }
        }
        __syncthreads();
        int node = (b << 8) | tid;
        if (node < N) cnt[node] = (int)c256[tid];
        return;
    }
    b -= nb;
    {                       // src role
        c256[tid] = 0;
        __syncthreads();
        int m = min(gcursS[b], BCAP);
        for (int j = tid; j < m; j += 256) {
            atomicAdd(&c256[regionS[(size_t)b * BCAP + j]], 1u);
        }
        __syncthreads();
        int on = min(*ovfS_n, OVFS_CAP);    // practically 0
        for (int k = tid; k < on; k += 256) {
            int v = ovfS[k];
            if ((v >> 8) == b) atomicAdd(&c256[v & 255], 1u);
        }
        __syncthreads();
        int node = (b << 8) | tid;
        if (node < N) {
            unsigned dg = c256[tid];
            dis[node] = dg ? rsqrtf((float)dg) : 0.0f;
        }
    }
}

// Wave-batched gather: lane l preloads (src, weight) for edge slot l, wave
// shfl-broadcasts; only the 256B row gather touches memory per edge.
__device__ __forceinline__ float2 gather_node(const unsigned* __restrict__ X,
                                              const unsigned short* __restrict__ csr,
                                              const int* __restrict__ cnt,
                                              const float* __restrict__ dis,
                                              const int* __restrict__ ovfD_n,
                                              const int2* __restrict__ ovfD,
                                              int node, int lane) {
    int c = min(cnt[node], CAP);
    float dd = dis[node];
    size_t base = (size_t)node * CAP;
    float ax0 = 0, ay0 = 0, ax1 = 0, ay1 = 0, ax2 = 0, ay2 = 0, ax3 = 0, ay3 = 0;
    for (int b0 = 0; b0 < c; b0 += 64) {
        int m = min(c - b0, 64);
        int sl = 0; float wl = 0.0f;
        if (lane < m) { sl = csr[base + b0 + lane]; wl = dis[sl] * dd; }
        int i = 0;
        for (; i + 3 < m; i += 4) {
            int s0 = __shfl(sl, i, 64),     s1 = __shfl(sl, i + 1, 64);
            int s2 = __shfl(sl, i + 2, 64), s3 = __shfl(sl, i + 3, 64);
            float w0 = __shfl(wl, i, 64),     w1 = __shfl(wl, i + 1, 64);
            float w2 = __shfl(wl, i + 2, 64), w3 = __shfl(wl, i + 3, 64);
            unsigned u0 = X[(size_t)s0 * 64 + lane];
            unsigned u1 = X[(size_t)s1 * 64 + lane];
            unsigned u2 = X[(size_t)s2 * 64 + lane];
            unsigned u3 = X[(size_t)s3 * 64 + lane];
            ax0 += w0 * bflo(u0); ay0 += w0 * bfhi(u0);
            ax1 += w1 * bflo(u1); ay1 += w1 * bfhi(u1);
            ax2 += w2 * bflo(u2); ay2 += w2 * bfhi(u2);
            ax3 += w3 * bflo(u3); ay3 += w3 * bfhi(u3);
        }
        for (; i < m; ++i) {
            int s0 = __shfl(sl, i, 64); float w0 = __shfl(wl, i, 64);
            unsigned u0 = X[(size_t)s0 * 64 + lane];
            ax0 += w0 * bflo(u0); ay0 += w0 * bfhi(u0);
        }
    }
    float2 acc = {ax0 + ax1 + ax2 + ax3, ay0 + ay1 + ay2 + ay3};
    int on = min(*ovfD_n, OVFD_CAP);   // practically 0; formal correctness
    for (int k = 0; k < on; ++k) {
        int2 eo = ovfD[k];
        if (eo.y == node) {
            float w = dis[eo.x] * dd;
            unsigned u = X[(size_t)eo.x * 64 + lane];
            acc.x += w * bflo(u); acc.y += w * bfhi(u);
        }
    }
    return acc;
}

__global__ void conv1_kernel(const unsigned* __restrict__ Xb, const unsigned short* __restrict__ csr,
                             const int* __restrict__ cnt, const float* __restrict__ dis,
                             const int* __restrict__ ovfD_n, const int2* __restrict__ ovfD,
                             unsigned* __restrict__ Hb, int n) {
    int node = (blockIdx.x * blockDim.x + threadIdx.x) >> 6;
    if (node >= n) return;
    int lane = threadIdx.x & 63;
    float2 acc = gather_node(Xb, csr, cnt, dis, ovfD_n, ovfD, node, lane);
    Hb[(size_t)node * 64 + lane] = packbf(acc.x, acc.y);
}

__global__ void conv2_kernel(const unsigned* __restrict__ Hb, const unsigned* __restrict__ Xb,
                             const unsigned short* __restrict__ csr,
                             const int* __restrict__ cnt, const float* __restrict__ dis,
                             const int* __restrict__ ovfD_n, const int2* __restrict__ ovfD,
                             float* __restrict__ out, int n) {
    int node = (blockIdx.x * blockDim.x + threadIdx.x) >> 6;
    if (node >= n) return;
    int lane = threadIdx.x & 63;
    float2 acc = gather_node(Hb, csr, cnt, dis, ovfD_n, ovfD, node, lane);
    unsigned hb = Hb[(size_t)node * 64 + lane];
    unsigned xb = Xb[(size_t)node * 64 + lane];
    float2 o;
    o.x = acc.x + bflo(hb) + bflo(xb);
    o.y = acc.y + bfhi(hb) + bfhi(xb);
    ((float2*)(out + (size_t)node * DIM))[lane] = o;
}

extern "C" void kernel_launch(void* const* d_in, const int* in_sizes, int n_in,
                              void* d_out, int out_size, void* d_ws, size_t ws_size,
                              hipStream_t stream) {
    const float* features   = (const float*)d_in[0];
    const float* preference = (const float*)d_in[1];
    const int*   edge_index = (const int*)d_in[2];

    const int N  = in_sizes[0] / DIM;   // 50000
    const int NU = in_sizes[1] / DIM;   // 10000
    const int E  = in_sizes[2] / 2;     // 1600000

    const int* src = edge_index;
    const int* dst = edge_index + E;
    float* out = (float*)d_out;

    const int nb = (N + 255) / 256;     // 196 node buckets

    // workspace layout (~46 MB; ws >= 51.4 MB proven in round 1)
    char* p = (char*)d_ws;
    unsigned* Xb = (unsigned*)p;              p += (size_t)N * 64 * sizeof(unsigned);
    unsigned* Hb = (unsigned*)p;              p += (size_t)N * 64 * sizeof(unsigned);
    unsigned short* csr = (unsigned short*)p; p += (size_t)N * CAP * sizeof(unsigned short);
    unsigned* regionD = (unsigned*)p;         p += (size_t)nb * BCAP * sizeof(unsigned);
    unsigned char* regionS = (unsigned char*)p; p += (size_t)nb * BCAP;
    p = (char*)(((size_t)p + 15) & ~(size_t)15);
    int* cnt = (int*)p;                       p += (size_t)N * sizeof(int);
    float* dis = (float*)p;                   p += (size_t)N * sizeof(float);
    int* hdr = (int*)p;                       p += 520 * sizeof(int);
    int* gcursD = hdr;            // 256 ints
    int* gcursS = hdr + 256;      // 256 ints
    int* ovfD_n = hdr + 512;
    int* ovfS_n = hdr + 513;
    int2* ovfD = (int2*)p;                    p += (size_t)OVFD_CAP * sizeof(int2);
    int* ovfS = (int*)p;                      p += (size_t)OVFS_CAP * sizeof(int);

    hipMemsetAsync(hdr, 0, 520 * sizeof(int), stream);

    int nb_scat = (E + EPB - 1) / EPB;
    int nb_norm = (N * 64 + 255) / 256;
    int nb_copy = (NU * DIM / 4 + 255) / 256;
    prep_kernel<<<nb_scat + nb_norm + nb_copy, 256, 0, stream>>>(
        features, preference, src, dst, Xb, regionD, regionS,
        gcursD, gcursS, ovfD_n, ovfD, ovfS_n, ovfS,
        out + (size_t)N * DIM, N, E, NU, nb, nb_scat, nb_norm);

    finalize_kernel<<<2 * nb, 256, 0, stream>>>(
        regionD, regionS, gcursD, gcursS, csr, cnt, dis,
        ovfD_n, ovfD, ovfS_n, ovfS, N, nb);

    int blocks = (N * 64 + 255) / 256;
    conv1_kernel<<<blocks, 256, 0, stream>>>(Xb, csr, cnt, dis, ovfD_n, ovfD, Hb, N);
    conv2_kernel<<<blocks, 256, 0, stream>>>(Hb, Xb, csr, cnt, dis, ovfD_n, ovfD, out, N);
}

// Round 7
// 139.543 us; speedup vs baseline: 2.7574x; 1.6598x over previous
//
#include <hip/hip_runtime.h>

#define DIM 128
#define CAP 96              // csr slots per node (mean in-deg 32; ovf fallback)
#define BCAP 10240          // region entries per 256-node bucket (mean ~8163, +23 sigma)
#define EPB 4096            // edges per scatter block
#define EPT 16              // edges per thread (EPB/256)
#define OVFD_CAP 32768
#define OVFS_CAP 32768

typedef float f32x2 __attribute__((ext_vector_type(2)));

// ---- fp8 e4m3 (OCP, gfx950 HW cvt) helpers: 2 fp8 in a ushort ----
__device__ __forceinline__ float2 fp8x2_to_f32(unsigned short u) {
    f32x2 r = __builtin_amdgcn_cvt_pk_f32_fp8((int)u, false);
    return make_float2(r.x, r.y);
}
__device__ __forceinline__ unsigned short f32_to_fp8x2(float a, float b) {
    return (unsigned short)(__builtin_amdgcn_cvt_pk_fp8_f32(a, b, 0, false) & 0xFFFF);
}

// Roles: [0,nb_scat): register-staged counting-sort of EPB edges into 256-node buckets
//        [..,+nb_norm): row L2-normalize features -> fp8 Xb8 + scales
//        [..,+nb_copy): preference passthrough (float4)
__global__ void __launch_bounds__(256) prep_kernel(
        const float* __restrict__ features, const float* __restrict__ preference,
        const int* __restrict__ src, const int* __restrict__ dst,
        unsigned short* __restrict__ Xb8, float* __restrict__ scales,
        unsigned* __restrict__ regionD, unsigned char* __restrict__ regionS,
        int* __restrict__ gcursD, int* __restrict__ gcursS,
        int* __restrict__ ovfD_n, int2* __restrict__ ovfD,
        int* __restrict__ ovfS_n, int* __restrict__ ovfS,
        float* __restrict__ out_pref,
        int N, int E, int NU, int nb, int nb_scat, int nb_norm) {
    __shared__ unsigned histD[256], histS[256];
    __shared__ unsigned scanD[256], scanS[256];
    __shared__ unsigned cursD[256], cursS[256];   // cursors during stage, bases after claim
    __shared__ unsigned wsumD[4], wsumS[4];
    __shared__ unsigned stageD[EPB];              // 16 KB: (bk<<24)|(dLow<<16)|src16
    __shared__ unsigned short stageS[EPB];        // 8 KB: (bk<<8)|sLow
    int b = blockIdx.x, tid = threadIdx.x;

    if (b < nb_scat) {
        int e0 = b * EPB;
        int m = min(E - e0, EPB);
        histD[tid] = 0; histS[tid] = 0;
        // load edges into registers, one coalesced pass
        unsigned packed[EPT];
        #pragma unroll
        for (int k = 0; k < EPT; ++k) {
            int j = tid + (k << 8);
            packed[k] = 0xFFFFFFFFu;
            if (j < m) {
                int s = src[e0 + j], d = dst[e0 + j];
                if (s != d) packed[k] = ((unsigned)d << 16) | (unsigned)s;
            }
        }
        __syncthreads();
        #pragma unroll
        for (int k = 0; k < EPT; ++k) {
            unsigned pk = packed[k];
            if (pk != 0xFFFFFFFFu) {
                atomicAdd(&histD[(pk >> 24)], 1u);          // d>>8
                atomicAdd(&histS[(pk >> 8) & 0xFFu], 1u);   // s>>8
            }
        }
        __syncthreads();
        // parallel exclusive scan of 256 bins (both hists)
        {
            int lane = tid & 63, wid = tid >> 6;
            unsigned vD = histD[tid], vS = histS[tid];
            unsigned iD = vD, iS = vS;
            #pragma unroll
            for (int off = 1; off < 64; off <<= 1) {
                unsigned tD = __shfl_up(iD, off, 64);
                unsigned tS = __shfl_up(iS, off, 64);
                if (lane >= off) { iD += tD; iS += tS; }
            }
            if (lane == 63) { wsumD[wid] = iD; wsumS[wid] = iS; }
            __syncthreads();
            if (tid == 0) { unsigned a = 0; for (int i = 0; i < 4; ++i) { unsigned t = wsumD[i]; wsumD[i] = a; a += t; } }
            if (tid == 64){ unsigned a = 0; for (int i = 0; i < 4; ++i) { unsigned t = wsumS[i]; wsumS[i] = a; a += t; } }
            __syncthreads();
            unsigned eD = iD - vD + wsumD[wid];
            unsigned eS = iS - vS + wsumS[wid];
            scanD[tid] = eD; scanS[tid] = eS;
            cursD[tid] = eD; cursS[tid] = eS;
        }
        __syncthreads();
        // stage into LDS grouped by bucket, bucket id in top bits
        #pragma unroll
        for (int k = 0; k < EPT; ++k) {
            unsigned pk = packed[k];
            if (pk != 0xFFFFFFFFu) {
                unsigned bkD = pk >> 24;
                unsigned p = atomicAdd(&cursD[bkD], 1u);
                stageD[p] = (bkD << 24) | ((pk >> 16 & 0xFFu) << 16) | (pk & 0xFFFFu);
                unsigned bkS = (pk >> 8) & 0xFFu;
                unsigned q = atomicAdd(&cursS[bkS], 1u);
                stageS[q] = (unsigned short)((bkS << 8) | (pk & 0xFFu));
            }
        }
        __syncthreads();
        // claim contiguous global runs (reuse curs as base)
        if (tid < nb) {
            unsigned c = histD[tid];
            cursD[tid] = c ? (unsigned)atomicAdd(&gcursD[tid], (int)c) : 0u;
            unsigned c2 = histS[tid];
            cursS[tid] = c2 ? (unsigned)atomicAdd(&gcursS[tid], (int)c2) : 0u;
        }
        __syncthreads();
        // one-pass flush D
        int mD = (int)(scanD[255] + histD[255]);
        for (int j = tid; j < mD; j += 256) {
            unsigned ent = stageD[j];
            unsigned bk = ent >> 24;
            unsigned gp = cursD[bk] + (unsigned)j - scanD[bk];
            if (gp < BCAP) regionD[(size_t)bk * BCAP + gp] = ent & 0x00FFFFFFu;
            else {
                int o = atomicAdd(ovfD_n, 1);
                if (o < OVFD_CAP) ovfD[o] = make_int2((int)(ent & 0xFFFFu),
                                                      (int)((bk << 8) | ((ent >> 16) & 0xFFu)));
            }
        }
        // one-pass flush S
        int mS = (int)(scanS[255] + histS[255]);
        for (int j = tid; j < mS; j += 256) {
            unsigned ent = stageS[j];
            unsigned bk = ent >> 8;
            unsigned gp = cursS[bk] + (unsigned)j - scanS[bk];
            if (gp < BCAP) regionS[(size_t)bk * BCAP + gp] = (unsigned char)(ent & 0xFFu);
            else {
                int o = atomicAdd(ovfS_n, 1);
                if (o < OVFS_CAP) ovfS[o] = (int)ent;
            }
        }
        return;
    }
    b -= nb_scat;
    if (b < nb_norm) {
        int t = b * 256 + tid;
        int row = t >> 6;
        if (row < N) {
            int lane = t & 63;
            float2 v = ((const float2*)(features + (size_t)row * DIM))[lane];
            float ss = v.x * v.x + v.y * v.y;
            #pragma unroll
            for (int off = 32; off >= 1; off >>= 1) ss += __shfl_xor(ss, off, 64);
            float scale = 1.0f / fmaxf(sqrtf(ss), 1e-12f);
            Xb8[(size_t)row * 64 + lane] = f32_to_fp8x2(v.x * scale, v.y * scale);
            if (lane == 0) scales[row] = scale;
        }
        return;
    }
    b -= nb_norm;
    {
        int i = b * 256 + tid;
        int n4 = NU * DIM / 4;
        if (i < n4) ((float4*)out_pref)[i] = ((const float4*)preference)[i];
    }
}

// Roles: [0,nb): per-dst-bucket slot assignment -> csr + cnt; [nb,2nb): src-degree -> dis.
__global__ void __launch_bounds__(256) finalize_kernel(
        const unsigned* __restrict__ regionD, const unsigned char* __restrict__ regionS,
        const int* __restrict__ gcursD, const int* __restrict__ gcursS,
        unsigned short* __restrict__ csr, int* __restrict__ cnt, float* __restrict__ dis,
        int* __restrict__ ovfD_n, int2* __restrict__ ovfD,
        const int* __restrict__ ovfS_n, const int* __restrict__ ovfS, int N, int nb) {
    __shared__ unsigned c256[256];
    int b = blockIdx.x, tid = threadIdx.x;
    if (b < nb) {           // dst role
        c256[tid] = 0;
        __syncthreads();
        int m = min(gcursD[b], BCAP);
        for (int j = tid; j < m; j += 256) {
            unsigned ent = regionD[(size_t)b * BCAP + j];
            unsigned dLow = ent >> 16;
            int s = (int)(ent & 0xFFFFu);
            unsigned pos = atomicAdd(&c256[dLow], 1u);
            int node = (b << 8) | (int)dLow;
            if (pos < CAP) csr[(size_t)node * CAP + pos] = (unsigned short)s;
            else {
                int o = atomicAdd(ovfD_n, 1);
                if (o < OVFD_CAP) ovfD[o] = make_int2(s, node);
            }
        }
        __syncthreads();
        int node = (b << 8) | tid;
        if (node < N) cnt[node] = (int)c256[tid];
        return;
    }
    b -= nb;
    {                       // src role
        c256[tid] = 0;
        __syncthreads();
        int m = min(gcursS[b], BCAP);
        for (int j = tid; j < m; j += 256)
            atomicAdd(&c256[regionS[(size_t)b * BCAP + j]], 1u);
        __syncthreads();
        int on = min(*ovfS_n, OVFS_CAP);    // practically 0
        for (int k = tid; k < on; k += 256) {
            int v = ovfS[k];
            if ((v >> 8) == b) atomicAdd(&c256[v & 255], 1u);
        }
        __syncthreads();
        int node = (b << 8) | tid;
        if (node < N) {
            unsigned dg = c256[tid];
            dis[node] = dg ? rsqrtf((float)dg) : 0.0f;
        }
    }
}

// Wave-batched fp8 gather: lane l preloads (src, weight) for slot l, wave shfls.
__device__ __forceinline__ float2 gather_node(const unsigned short* __restrict__ X8,
                                              const unsigned short* __restrict__ csr,
                                              const int* __restrict__ cnt,
                                              const float* __restrict__ dis,
                                              const int* __restrict__ ovfD_n,
                                              const int2* __restrict__ ovfD,
                                              int node, int lane) {
    int c = min(cnt[node], CAP);
    float dd = dis[node];
    size_t base = (size_t)node * CAP;
    float ax0 = 0, ay0 = 0, ax1 = 0, ay1 = 0, ax2 = 0, ay2 = 0, ax3 = 0, ay3 = 0;
    for (int b0 = 0; b0 < c; b0 += 64) {
        int m = min(c - b0, 64);
        int sl = 0; float wl = 0.0f;
        if (lane < m) { sl = csr[base + b0 + lane]; wl = dis[sl] * dd; }
        int i = 0;
        for (; i + 3 < m; i += 4) {
            int s0 = __shfl(sl, i, 64),     s1 = __shfl(sl, i + 1, 64);
            int s2 = __shfl(sl, i + 2, 64), s3 = __shfl(sl, i + 3, 64);
            float w0 = __shfl(wl, i, 64),     w1 = __shfl(wl, i + 1, 64);
            float w2 = __shfl(wl, i + 2, 64), w3 = __shfl(wl, i + 3, 64);
            float2 v0 = fp8x2_to_f32(X8[(size_t)s0 * 64 + lane]);
            float2 v1 = fp8x2_to_f32(X8[(size_t)s1 * 64 + lane]);
            float2 v2 = fp8x2_to_f32(X8[(size_t)s2 * 64 + lane]);
            float2 v3 = fp8x2_to_f32(X8[(size_t)s3 * 64 + lane]);
            ax0 += w0 * v0.x; ay0 += w0 * v0.y;
            ax1 += w1 * v1.x; ay1 += w1 * v1.y;
            ax2 += w2 * v2.x; ay2 += w2 * v2.y;
            ax3 += w3 * v3.x; ay3 += w3 * v3.y;
        }
        for (; i < m; ++i) {
            int s0 = __shfl(sl, i, 64); float w0 = __shfl(wl, i, 64);
            float2 v0 = fp8x2_to_f32(X8[(size_t)s0 * 64 + lane]);
            ax0 += w0 * v0.x; ay0 += w0 * v0.y;
        }
    }
    float2 acc = {ax0 + ax1 + ax2 + ax3, ay0 + ay1 + ay2 + ay3};
    int on = min(*ovfD_n, OVFD_CAP);   // practically 0; formal correctness
    for (int k = 0; k < on; ++k) {
        int2 eo = ovfD[k];
        if (eo.y == node) {
            float w = dis[eo.x] * dd;
            float2 v = fp8x2_to_f32(X8[(size_t)eo.x * 64 + lane]);
            acc.x += w * v.x; acc.y += w * v.y;
        }
    }
    return acc;
}

__global__ void __launch_bounds__(256) conv1_kernel(
        const unsigned short* __restrict__ Xb8, const unsigned short* __restrict__ csr,
        const int* __restrict__ cnt, const float* __restrict__ dis,
        const int* __restrict__ ovfD_n, const int2* __restrict__ ovfD,
        unsigned short* __restrict__ Hb8, int n) {
    int node = (blockIdx.x * blockDim.x + threadIdx.x) >> 6;
    if (node >= n) return;
    int lane = threadIdx.x & 63;
    float2 acc = gather_node(Xb8, csr, cnt, dis, ovfD_n, ovfD, node, lane);
    Hb8[(size_t)node * 64 + lane] = f32_to_fp8x2(acc.x, acc.y);
}

// out = conv(h) + h + x, with x recomputed full-precision from features*scale.
__global__ void __launch_bounds__(256) conv2_kernel(
        const unsigned short* __restrict__ Hb8, const float* __restrict__ features,
        const float* __restrict__ scales, const unsigned short* __restrict__ csr,
        const int* __restrict__ cnt, const float* __restrict__ dis,
        const int* __restrict__ ovfD_n, const int2* __restrict__ ovfD,
        float* __restrict__ out, int n) {
    int node = (blockIdx.x * blockDim.x + threadIdx.x) >> 6;
    if (node >= n) return;
    int lane = threadIdx.x & 63;
    float2 acc = gather_node(Hb8, csr, cnt, dis, ovfD_n, ovfD, node, lane);
    float2 hv = fp8x2_to_f32(Hb8[(size_t)node * 64 + lane]);
    float2 f = ((const float2*)(features + (size_t)node * DIM))[lane];
    float sc = scales[node];
    float2 o;
    o.x = acc.x + hv.x + f.x * sc;
    o.y = acc.y + hv.y + f.y * sc;
    ((float2*)(out + (size_t)node * DIM))[lane] = o;
}

extern "C" void kernel_launch(void* const* d_in, const int* in_sizes, int n_in,
                              void* d_out, int out_size, void* d_ws, size_t ws_size,
                              hipStream_t stream) {
    const float* features   = (const float*)d_in[0];
    const float* preference = (const float*)d_in[1];
    const int*   edge_index = (const int*)d_in[2];

    const int N  = in_sizes[0] / DIM;   // 50000
    const int NU = in_sizes[1] / DIM;   // 10000
    const int E  = in_sizes[2] / 2;     // 1600000

    const int* src = edge_index;
    const int* dst = edge_index + E;
    float* out = (float*)d_out;

    const int nb = (N + 255) / 256;     // 196 node buckets

    // workspace layout (~34 MB; ws >= 55 MB proven in round 2)
    char* p = (char*)d_ws;
    unsigned short* Xb8 = (unsigned short*)p; p += (size_t)N * 64 * sizeof(unsigned short);
    unsigned short* Hb8 = (unsigned short*)p; p += (size_t)N * 64 * sizeof(unsigned short);
    unsigned short* csr = (unsigned short*)p; p += (size_t)N * CAP * sizeof(unsigned short);
    unsigned* regionD = (unsigned*)p;         p += (size_t)nb * BCAP * sizeof(unsigned);
    unsigned char* regionS = (unsigned char*)p; p += (size_t)nb * BCAP;
    p = (char*)(((size_t)p + 15) & ~(size_t)15);
    int* cnt = (int*)p;                       p += (size_t)N * sizeof(int);
    float* dis = (float*)p;                   p += (size_t)N * sizeof(float);
    float* scales = (float*)p;                p += (size_t)N * sizeof(float);
    int* hdr = (int*)p;                       p += 520 * sizeof(int);
    int* gcursD = hdr;            // 256 ints
    int* gcursS = hdr + 256;      // 256 ints
    int* ovfD_n = hdr + 512;
    int* ovfS_n = hdr + 513;
    int2* ovfD = (int2*)p;                    p += (size_t)OVFD_CAP * sizeof(int2);
    int* ovfS = (int*)p;                      p += (size_t)OVFS_CAP * sizeof(int);

    hipMemsetAsync(hdr, 0, 520 * sizeof(int), stream);

    int nb_scat = (E + EPB - 1) / EPB;
    int nb_norm = (N * 64 + 255) / 256;
    int nb_copy = (NU * DIM / 4 + 255) / 256;
    prep_kernel<<<nb_scat + nb_norm + nb_copy, 256, 0, stream>>>(
        features, preference, src, dst, Xb8, scales, regionD, regionS,
        gcursD, gcursS, ovfD_n, ovfD, ovfS_n, ovfS,
        out + (size_t)N * DIM, N, E, NU, nb, nb_scat, nb_norm);

    finalize_kernel<<<2 * nb, 256, 0, stream>>>(
        regionD, regionS, gcursD, gcursS, csr, cnt, dis,
        ovfD_n, ovfD, ovfS_n, ovfS, N, nb);

    int blocks = (N * 64 + 255) / 256;
    conv1_kernel<<<blocks, 256, 0, stream>>>(Xb8, csr, cnt, dis, ovfD_n, ovfD, Hb8, N);
    conv2_kernel<<<blocks, 256, 0, stream>>>(Hb8, features, scales, csr, cnt, dis,
                                             ovfD_n, ovfD, out, N);
}

// Round 9
// 121.283 us; speedup vs baseline: 3.1726x; 1.1506x over previous
//
#include <hip/hip_runtime.h>

#define DIM 128
#define CAP 96              // csr slots per node (mean in-deg 32; ovf fallback)
#define BCAP 10240          // region entries per 256-node bucket (mean ~8163, +23 sigma)
#define EPB 4096            // edges per scatter block
#define EPT 16              // edges per thread (EPB/256)
#define GL 16               // lanes per node group in conv kernels
#define OVFD_CAP 32768
#define OVFS_CAP 32768

typedef float f32x2 __attribute__((ext_vector_type(2)));

// ---- fp8 e4m3 (OCP, gfx950 HW cvt) helpers ----
template <bool HI>
__device__ __forceinline__ float2 fp8x2_to_f32(unsigned u) {
    f32x2 r = __builtin_amdgcn_cvt_pk_f32_fp8((int)u, HI);
    return make_float2(r.x, r.y);
}
__device__ __forceinline__ unsigned short f32_to_fp8x2(float a, float b) {
    return (unsigned short)(__builtin_amdgcn_cvt_pk_fp8_f32(a, b, 0, false) & 0xFFFF);
}

// Roles: [0,nb_scat): register-staged counting-sort of EPB edges into 256-node buckets
//        [..,+nb_norm): row L2-normalize features -> fp8 Xb8 + scales
//        [..,+nb_copy): preference passthrough (float4)
__global__ void __launch_bounds__(256) prep_kernel(
        const float* __restrict__ features, const float* __restrict__ preference,
        const int* __restrict__ src, const int* __restrict__ dst,
        unsigned short* __restrict__ Xb8, float* __restrict__ scales,
        unsigned* __restrict__ regionD, unsigned char* __restrict__ regionS,
        int* __restrict__ gcursD, int* __restrict__ gcursS,
        int* __restrict__ ovfD_n, int2* __restrict__ ovfD,
        int* __restrict__ ovfS_n, int* __restrict__ ovfS,
        float* __restrict__ out_pref,
        int N, int E, int NU, int nb, int nb_scat, int nb_norm) {
    __shared__ unsigned histD[256], histS[256];
    __shared__ unsigned scanD[256], scanS[256];
    __shared__ unsigned cursD[256], cursS[256];   // cursors during stage, bases after claim
    __shared__ unsigned wsumD[4], wsumS[4];
    __shared__ unsigned stageD[EPB];              // 16 KB: (bk<<24)|(dLow<<16)|src16
    __shared__ unsigned short stageS[EPB];        // 8 KB: (bk<<8)|sLow
    int b = blockIdx.x, tid = threadIdx.x;

    if (b < nb_scat) {
        int e0 = b * EPB;
        int m = min(E - e0, EPB);
        histD[tid] = 0; histS[tid] = 0;
        unsigned packed[EPT];
        #pragma unroll
        for (int k = 0; k < EPT; ++k) {
            int j = tid + (k << 8);
            packed[k] = 0xFFFFFFFFu;
            if (j < m) {
                int s = src[e0 + j], d = dst[e0 + j];
                if (s != d) packed[k] = ((unsigned)d << 16) | (unsigned)s;
            }
        }
        __syncthreads();
        #pragma unroll
        for (int k = 0; k < EPT; ++k) {
            unsigned pk = packed[k];
            if (pk != 0xFFFFFFFFu) {
                atomicAdd(&histD[(pk >> 24)], 1u);
                atomicAdd(&histS[(pk >> 8) & 0xFFu], 1u);
            }
        }
        __syncthreads();
        {   // parallel exclusive scan of 256 bins (both hists)
            int lane = tid & 63, wid = tid >> 6;
            unsigned vD = histD[tid], vS = histS[tid];
            unsigned iD = vD, iS = vS;
            #pragma unroll
            for (int off = 1; off < 64; off <<= 1) {
                unsigned tD = __shfl_up(iD, off, 64);
                unsigned tS = __shfl_up(iS, off, 64);
                if (lane >= off) { iD += tD; iS += tS; }
            }
            if (lane == 63) { wsumD[wid] = iD; wsumS[wid] = iS; }
            __syncthreads();
            if (tid == 0) { unsigned a = 0; for (int i = 0; i < 4; ++i) { unsigned t = wsumD[i]; wsumD[i] = a; a += t; } }
            if (tid == 64){ unsigned a = 0; for (int i = 0; i < 4; ++i) { unsigned t = wsumS[i]; wsumS[i] = a; a += t; } }
            __syncthreads();
            unsigned eD = iD - vD + wsumD[wid];
            unsigned eS = iS - vS + wsumS[wid];
            scanD[tid] = eD; scanS[tid] = eS;
            cursD[tid] = eD; cursS[tid] = eS;
        }
        __syncthreads();
        #pragma unroll
        for (int k = 0; k < EPT; ++k) {
            unsigned pk = packed[k];
            if (pk != 0xFFFFFFFFu) {
                unsigned bkD = pk >> 24;
                unsigned p = atomicAdd(&cursD[bkD], 1u);
                stageD[p] = (bkD << 24) | ((pk >> 16 & 0xFFu) << 16) | (pk & 0xFFFFu);
                unsigned bkS = (pk >> 8) & 0xFFu;
                unsigned q = atomicAdd(&cursS[bkS], 1u);
                stageS[q] = (unsigned short)((bkS << 8) | (pk & 0xFFu));
            }
        }
        __syncthreads();
        if (tid < nb) {   // claim contiguous global runs (reuse curs as base)
            unsigned c = histD[tid];
            cursD[tid] = c ? (unsigned)atomicAdd(&gcursD[tid], (int)c) : 0u;
            unsigned c2 = histS[tid];
            cursS[tid] = c2 ? (unsigned)atomicAdd(&gcursS[tid], (int)c2) : 0u;
        }
        __syncthreads();
        int mD = (int)(scanD[255] + histD[255]);
        for (int j = tid; j < mD; j += 256) {   // one-pass flush D
            unsigned ent = stageD[j];
            unsigned bk = ent >> 24;
            unsigned gp = cursD[bk] + (unsigned)j - scanD[bk];
            if (gp < BCAP) regionD[(size_t)bk * BCAP + gp] = ent & 0x00FFFFFFu;
            else {
                int o = atomicAdd(ovfD_n, 1);
                if (o < OVFD_CAP) ovfD[o] = make_int2((int)(ent & 0xFFFFu),
                                                      (int)((bk << 8) | ((ent >> 16) & 0xFFu)));
            }
        }
        int mS = (int)(scanS[255] + histS[255]);
        for (int j = tid; j < mS; j += 256) {   // one-pass flush S
            unsigned ent = stageS[j];
            unsigned bk = ent >> 8;
            unsigned gp = cursS[bk] + (unsigned)j - scanS[bk];
            if (gp < BCAP) regionS[(size_t)bk * BCAP + gp] = (unsigned char)(ent & 0xFFu);
            else {
                int o = atomicAdd(ovfS_n, 1);
                if (o < OVFS_CAP) ovfS[o] = (int)ent;
            }
        }
        return;
    }
    b -= nb_scat;
    if (b < nb_norm) {
        int t = b * 256 + tid;
        int row = t >> 6;
        if (row < N) {
            int lane = t & 63;
            float2 v = ((const float2*)(features + (size_t)row * DIM))[lane];
            float ss = v.x * v.x + v.y * v.y;
            #pragma unroll
            for (int off = 32; off >= 1; off >>= 1) ss += __shfl_xor(ss, off, 64);
            float scale = 1.0f / fmaxf(sqrtf(ss), 1e-12f);
            Xb8[(size_t)row * 64 + lane] = f32_to_fp8x2(v.x * scale, v.y * scale);
            if (lane == 0) scales[row] = scale;
        }
        return;
    }
    b -= nb_norm;
    {
        int i = b * 256 + tid;
        int n4 = NU * DIM / 4;
        if (i < n4) ((float4*)out_pref)[i] = ((const float4*)preference)[i];
    }
}

// Roles: [0,nb): per-dst-bucket slot assignment -> csr + cnt; [nb,2nb): src-degree -> dis.
__global__ void __launch_bounds__(256) finalize_kernel(
        const unsigned* __restrict__ regionD, const unsigned char* __restrict__ regionS,
        const int* __restrict__ gcursD, const int* __restrict__ gcursS,
        unsigned short* __restrict__ csr, int* __restrict__ cnt, float* __restrict__ dis,
        int* __restrict__ ovfD_n, int2* __restrict__ ovfD,
        const int* __restrict__ ovfS_n, const int* __restrict__ ovfS, int N, int nb) {
    __shared__ unsigned c256[256];
    int b = blockIdx.x, tid = threadIdx.x;
    if (b < nb) {           // dst role
        c256[tid] = 0;
        __syncthreads();
        int m = min(gcursD[b], BCAP);
        for (int j = tid; j < m; j += 256) {
            unsigned ent = regionD[(size_t)b * BCAP + j];
            unsigned dLow = ent >> 16;
            int s = (int)(ent & 0xFFFFu);
            unsigned pos = atomicAdd(&c256[dLow], 1u);
            int node = (b << 8) | (int)dLow;
            if (pos < CAP) csr[(size_t)node * CAP + pos] = (unsigned short)s;
            else {
                int o = atomicAdd(ovfD_n, 1);
                if (o < OVFD_CAP) ovfD[o] = make_int2(s, node);
            }
        }
        __syncthreads();
        int node = (b << 8) | tid;
        if (node < N) cnt[node] = (int)c256[tid];
        return;
    }
    b -= nb;
    {                       // src role
        c256[tid] = 0;
        __syncthreads();
        int m = min(gcursS[b], BCAP);
        for (int j = tid; j < m; j += 256)
            atomicAdd(&c256[regionS[(size_t)b * BCAP + j]], 1u);
        __syncthreads();
        int on = min(*ovfS_n, OVFS_CAP);    // practically 0
        for (int k = tid; k < on; k += 256) {
            int v = ovfS[k];
            if ((v >> 8) == b) atomicAdd(&c256[v & 255], 1u);
        }
        __syncthreads();
        int node = (b << 8) | tid;
        if (node < N) {
            unsigned dg = c256[tid];
            dis[node] = dg ? rsqrtf((float)dg) : 0.0f;
        }
    }
}

// Accumulate 8 dims (one uint2 = 8 fp8) into a[0..7]
#define ACC8(a, u, w)                                                     \
    do {                                                                  \
        float2 _p0 = fp8x2_to_f32<false>((u).x);                          \
        float2 _p1 = fp8x2_to_f32<true>((u).x);                           \
        float2 _p2 = fp8x2_to_f32<false>((u).y);                          \
        float2 _p3 = fp8x2_to_f32<true>((u).y);                           \
        a[0] += (w) * _p0.x; a[1] += (w) * _p0.y;                         \
        a[2] += (w) * _p1.x; a[3] += (w) * _p1.y;                         \
        a[4] += (w) * _p2.x; a[5] += (w) * _p2.y;                         \
        a[6] += (w) * _p3.x; a[7] += (w) * _p3.y;                         \
    } while (0)

// 16-lane-group gather: group owns one node; lane owns 8 dims (uint2).
// One wave carries 4 nodes -> 512B per wave-wide load instruction.
__device__ __forceinline__ void gather_node16(const uint2* __restrict__ X8,
                                              const unsigned short* __restrict__ csr,
                                              const int* __restrict__ cnt,
                                              const float* __restrict__ dis,
                                              const int* __restrict__ ovfD_n,
                                              const int2* __restrict__ ovfD,
                                              int node, int lane, float* a) {
    int c = min(cnt[node], CAP);
    float dd = dis[node];
    size_t base = (size_t)node * CAP;
    float b8[8];
    #pragma unroll
    for (int j = 0; j < 8; ++j) { a[j] = 0.0f; b8[j] = 0.0f; }
    for (int b0 = 0; b0 < c; b0 += GL) {
        int m = min(c - b0, GL);
        int sl = 0; float wl = 0.0f;
        if (lane < m) { sl = csr[base + b0 + lane]; wl = dis[sl] * dd; }
        int i = 0;
        for (; i + 1 < m; i += 2) {
            int s0 = __shfl(sl, i, GL), s1 = __shfl(sl, i + 1, GL);
            float w0 = __shfl(wl, i, GL), w1 = __shfl(wl, i + 1, GL);
            uint2 u0 = X8[(size_t)s0 * GL + lane];
            uint2 u1 = X8[(size_t)s1 * GL + lane];
            ACC8(a, u0, w0);
            ACC8(b8, u1, w1);
        }
        if (i < m) {
            int s0 = __shfl(sl, i, GL);
            float w0 = __shfl(wl, i, GL);
            uint2 u0 = X8[(size_t)s0 * GL + lane];
            ACC8(a, u0, w0);
        }
    }
    #pragma unroll
    for (int j = 0; j < 8; ++j) a[j] += b8[j];
    int on = min(*ovfD_n, OVFD_CAP);   // practically 0; formal correctness
    for (int k = 0; k < on; ++k) {
        int2 eo = ovfD[k];
        if (eo.y == node) {
            float w = dis[eo.x] * dd;
            uint2 u = X8[(size_t)eo.x * GL + lane];
            ACC8(a, u, w);
        }
    }
}

__global__ void __launch_bounds__(256) conv1_kernel(
        const uint2* __restrict__ Xb8, const unsigned short* __restrict__ csr,
        const int* __restrict__ cnt, const float* __restrict__ dis,
        const int* __restrict__ ovfD_n, const int2* __restrict__ ovfD,
        uint2* __restrict__ Hb8, int n) {
    int t = blockIdx.x * 256 + threadIdx.x;
    int node = t >> 4;
    if (node >= n) return;
    int lane = threadIdx.x & (GL - 1);
    float a[8];
    gather_node16(Xb8, csr, cnt, dis, ovfD_n, ovfD, node, lane, a);
    unsigned lo = (unsigned)__builtin_amdgcn_cvt_pk_fp8_f32(a[0], a[1], 0, false);
    lo = (unsigned)__builtin_amdgcn_cvt_pk_fp8_f32(a[2], a[3], (int)lo, true);
    unsigned hi = (unsigned)__builtin_amdgcn_cvt_pk_fp8_f32(a[4], a[5], 0, false);
    hi = (unsigned)__builtin_amdgcn_cvt_pk_fp8_f32(a[6], a[7], (int)hi, true);
    Hb8[(size_t)node * GL + lane] = make_uint2(lo, hi);
}

// out = conv(h) + h + x, x recomputed full-precision from features*scale.
__global__ void __launch_bounds__(256) conv2_kernel(
        const uint2* __restrict__ Hb8, const float* __restrict__ features,
        const float* __restrict__ scales, const unsigned short* __restrict__ csr,
        const int* __restrict__ cnt, const float* __restrict__ dis,
        const int* __restrict__ ovfD_n, const int2* __restrict__ ovfD,
        float* __restrict__ out, int n) {
    int t = blockIdx.x * 256 + threadIdx.x;
    int node = t >> 4;
    if (node >= n) return;
    int lane = threadIdx.x & (GL - 1);
    float a[8];
    gather_node16(Hb8, csr, cnt, dis, ovfD_n, ovfD, node, lane, a);
    uint2 hu = Hb8[(size_t)node * GL + lane];
    float2 h0 = fp8x2_to_f32<false>(hu.x), h1 = fp8x2_to_f32<true>(hu.x);
    float2 h2 = fp8x2_to_f32<false>(hu.y), h3 = fp8x2_to_f32<true>(hu.y);
    const float* frow = features + (size_t)node * DIM + lane * 8;
    float4 f0 = *(const float4*)frow;
    float4 f1 = *(const float4*)(frow + 4);
    float sc = scales[node];
    float4 o0, o1;
    o0.x = a[0] + h0.x + f0.x * sc; o0.y = a[1] + h0.y + f0.y * sc;
    o0.z = a[2] + h1.x + f0.z * sc; o0.w = a[3] + h1.y + f0.w * sc;
    o1.x = a[4] + h2.x + f1.x * sc; o1.y = a[5] + h2.y + f1.y * sc;
    o1.z = a[6] + h3.x + f1.z * sc; o1.w = a[7] + h3.y + f1.w * sc;
    float* orow = out + (size_t)node * DIM + lane * 8;
    *(float4*)orow = o0;
    *(float4*)(orow + 4) = o1;
}

extern "C" void kernel_launch(void* const* d_in, const int* in_sizes, int n_in,
                              void* d_out, int out_size, void* d_ws, size_t ws_size,
                              hipStream_t stream) {
    const float* features   = (const float*)d_in[0];
    const float* preference = (const float*)d_in[1];
    const int*   edge_index = (const int*)d_in[2];

    const int N  = in_sizes[0] / DIM;   // 50000
    const int NU = in_sizes[1] / DIM;   // 10000
    const int E  = in_sizes[2] / 2;     // 1600000

    const int* src = edge_index;
    const int* dst = edge_index + E;
    float* out = (float*)d_out;

    const int nb = (N + 255) / 256;     // 196 node buckets

    // workspace layout (~34 MB; ws >= 55 MB proven in round 2)
    char* p = (char*)d_ws;
    unsigned short* Xb8 = (unsigned short*)p; p += (size_t)N * 64 * sizeof(unsigned short);
    unsigned short* Hb8 = (unsigned short*)p; p += (size_t)N * 64 * sizeof(unsigned short);
    unsigned short* csr = (unsigned short*)p; p += (size_t)N * CAP * sizeof(unsigned short);
    unsigned* regionD = (unsigned*)p;         p += (size_t)nb * BCAP * sizeof(unsigned);
    unsigned char* regionS = (unsigned char*)p; p += (size_t)nb * BCAP;
    p = (char*)(((size_t)p + 15) & ~(size_t)15);
    int* cnt = (int*)p;                       p += (size_t)N * sizeof(int);
    float* dis = (float*)p;                   p += (size_t)N * sizeof(float);
    float* scales = (float*)p;                p += (size_t)N * sizeof(float);
    int* hdr = (int*)p;                       p += 520 * sizeof(int);
    int* gcursD = hdr;            // 256 ints
    int* gcursS = hdr + 256;      // 256 ints
    int* ovfD_n = hdr + 512;
    int* ovfS_n = hdr + 513;
    int2* ovfD = (int2*)p;                    p += (size_t)OVFD_CAP * sizeof(int2);
    int* ovfS = (int*)p;                      p += (size_t)OVFS_CAP * sizeof(int);

    (void)hipMemsetAsync(hdr, 0, 520 * sizeof(int), stream);

    int nb_scat = (E + EPB - 1) / EPB;
    int nb_norm = (N * 64 + 255) / 256;
    int nb_copy = (NU * DIM / 4 + 255) / 256;
    prep_kernel<<<nb_scat + nb_norm + nb_copy, 256, 0, stream>>>(
        features, preference, src, dst, Xb8, scales, regionD, regionS,
        gcursD, gcursS, ovfD_n, ovfD, ovfS_n, ovfS,
        out + (size_t)N * DIM, N, E, NU, nb, nb_scat, nb_norm);

    finalize_kernel<<<2 * nb, 256, 0, stream>>>(
        regionD, regionS, gcursD, gcursS, csr, cnt, dis,
        ovfD_n, ovfD, ovfS_n, ovfS, N, nb);

    int cblocks = (N * GL + 255) / 256;
    conv1_kernel<<<cblocks, 256, 0, stream>>>((const uint2*)Xb8, csr, cnt, dis,
                                              ovfD_n, ovfD, (uint2*)Hb8, N);
    conv2_kernel<<<cblocks, 256, 0, stream>>>((const uint2*)Hb8, features, scales,
                                              csr, cnt, dis, ovfD_n, ovfD, out, N);
}